// Round 3
// baseline (1575.843 us; speedup 1.0000x reference)
//
#include <hip/hip_runtime.h>
#include <hip/hip_bf16.h>
#include <cstdint>
#include <cstddef>

typedef __bf16 bf16;
typedef __bf16 bf16x8 __attribute__((ext_vector_type(8)));
typedef __bf16 bf16x4v __attribute__((ext_vector_type(4)));
typedef float f32x4 __attribute__((ext_vector_type(4)));

#define NB 2
#define NS 2048
#define NHID 2304
#define NHEADS 8
#define NKVH 4
#define HDIM 256
#define NFF 9216
#define NROWS (NB * NS)      // 4096
#define SCALE_F 0.0625f      // 256^-0.5
#define SOFTCAP_F 50.0f

// async global->LDS DMA, 16B per lane; LDS dest = wave-uniform base + lane*16
#define ASYNC16(ldsp, gp)                                                     \
    __builtin_amdgcn_global_load_lds(                                         \
        (__attribute__((address_space(1))) void*)(gp),                        \
        (__attribute__((address_space(3))) void*)(ldsp), 16, 0, 0)

__device__ __forceinline__ float fast_tanh(float x) {
    x = fminf(fmaxf(x, -10.f), 10.f);
    float e = __expf(2.f * x);
    return (e - 1.f) / (e + 1.f);
}

// ---------------------------------------------------------------------------
// Partial transpose+convert: reads W[k][n] f32 for k in [k0, k0+64*gridK),
// writes bf16 dst[n*dstK + dstOff + (k-k0)].  64x64 tiles.
// ---------------------------------------------------------------------------
__global__ __launch_bounds__(256)
void transpose_cvt_part(const float* __restrict__ W, int N, int k0,
                        bf16* __restrict__ dst, int dstK, int dstOff) {
    __shared__ float tile[64][65];
    const int ntiles = N >> 6;
    const int tk = blockIdx.x / ntiles, tn = blockIdx.x % ntiles;
    const int kk0 = k0 + (tk << 6), n0 = tn << 6;
    const int tr = threadIdx.x >> 4, tc = threadIdx.x & 15;
#pragma unroll
    for (int j = 0; j < 4; ++j) {
        const int r = j * 16 + tr;
        const float4 v = *(const float4*)&W[(size_t)(kk0 + r) * N + n0 + tc * 4];
        tile[r][tc * 4 + 0] = v.x; tile[r][tc * 4 + 1] = v.y;
        tile[r][tc * 4 + 2] = v.z; tile[r][tc * 4 + 3] = v.w;
    }
    __syncthreads();
#pragma unroll
    for (int j = 0; j < 4; ++j) {
        const int n = j * 16 + tr;
        bf16x4v o;
        o.x = (bf16)tile[tc * 4 + 0][n];
        o.y = (bf16)tile[tc * 4 + 1][n];
        o.z = (bf16)tile[tc * 4 + 2][n];
        o.w = (bf16)tile[tc * 4 + 3][n];
        *(bf16x4v*)&dst[(size_t)(n0 + n) * dstK + dstOff + (tk << 6) + tc * 4] = o;
    }
}

// copy temp[n][0..srcK) -> dst[n*dstK + 0..srcK), 16B chunks
__global__ __launch_bounds__(256)
void copy_expand(const bf16* __restrict__ src, bf16* __restrict__ dst,
                 int srcK, int dstK, int total) {
    const int idx = blockIdx.x * 256 + threadIdx.x;
    if (idx >= total) return;
    const int cpr = srcK >> 3;
    const int n = idx / cpr, c = idx % cpr;
    *(uint4*)&dst[(size_t)n * dstK + c * 8] = *(const uint4*)&src[(size_t)n * srcK + c * 8];
}

// ---------------------------------------------------------------------------
// RMSNorm: out = [res +] rmsnorm(src, g).  One block per row, 256 thr, H=2304.
// ---------------------------------------------------------------------------
template <bool ADD, bool OBF>
__global__ __launch_bounds__(256)
void rmsnorm_k(const float* __restrict__ src, const float* __restrict__ res,
               const float* __restrict__ g, void* __restrict__ out) {
    const int row = blockIdx.x;
    const float* xr = src + (size_t)row * NHID;
    float vals[9];
    float ss = 0.f;
#pragma unroll
    for (int j = 0; j < 9; ++j) {
        vals[j] = xr[threadIdx.x + j * 256];
        ss += vals[j] * vals[j];
    }
#pragma unroll
    for (int off = 32; off > 0; off >>= 1) ss += __shfl_xor(ss, off);
    __shared__ float wss[4];
    if ((threadIdx.x & 63) == 0) wss[threadIdx.x >> 6] = ss;
    __syncthreads();
    const float scale = rsqrtf((wss[0] + wss[1] + wss[2] + wss[3]) * (1.f / NHID) + 1e-6f);
#pragma unroll
    for (int j = 0; j < 9; ++j) {
        const int c = threadIdx.x + j * 256;
        float v = vals[j] * scale * (1.f + g[c]);
        if constexpr (ADD) v += res[(size_t)row * NHID + c];
        if constexpr (OBF) ((bf16*)out)[(size_t)row * NHID + c] = (bf16)v;
        else               ((float*)out)[(size_t)row * NHID + c] = v;
    }
}

// ---------------------------------------------------------------------------
// RoPE in-place on bf16 q [4096][2048] and k [4096][1024].
// ---------------------------------------------------------------------------
__global__ __launch_bounds__(256)
void rope_k(bf16* __restrict__ q, bf16* __restrict__ k) {
    const int idx = blockIdx.x * 256 + threadIdx.x;
    const int i = idx & 127;
    const int t = idx >> 7;
    const int head = t % 12;
    const int row = t / 12;
    const int s = row & (NS - 1);
    const float ang = (float)s * exp2f(-(float)i * 0.10381025296523007f);
    float sn, cs;
    sincosf(ang, &sn, &cs);
    bf16* base = (head < 8) ? (q + (size_t)row * 2048 + head * 256 + i)
                            : (k + (size_t)row * 1024 + (head - 8) * 256 + i);
    const float x1 = (float)base[0], x2 = (float)base[128];
    base[0]   = (bf16)(x1 * cs - x2 * sn);
    base[128] = (bf16)(x2 * cs + x1 * sn);
}

// ---------------------------------------------------------------------------
// gemm8p: 8-phase pipelined 256x256-tile GEMM (m201 template, plain HIP).
// C[M][N] = A[M][K] @ Bt[N][K]^T.  512 thr = 8 waves (2M x 4N), per-wave
// 128x64 output = acc[8][4] of 16x16 frags.  BK=64 split into K-halves of 32.
//
// LDS 128 KiB = 2 buffers x {A: 256x64, B: 256x64} bf16, each stored as two
// 16 KiB K-halves [256 rows][32 k].
//
// T2 bank-conflict swizzle (rule #21: both-sides-or-neither with
// global_load_lds): each 64-B row has 4 16-B slots; logical slot s lives at
// physical slot p = s ^ ((row>>1)&3).  global_load_lds writes LDS linearly,
// so the involution is applied to the *global source* k-offset in
// stage_half (lane l covers logical slot (l&3)^((l>>3)&3) of its row) and
// to the ds_read byte offset (quad ^ ((lq>>1)&3)).  Bank proof: lane lq
// reading rows c+lq at logical slot quad hits bank-group
// (4*lq + quad^((lq>>1)&3)) mod 8 -> all 8 groups over lq=0..7, 2 lanes
// each = conflict-free (was 8-way: R*4 mod 8 is 2-valued).
//
// Per K-tile t (buffer b=t&1), 4 phases (kk x m-half), each:
//   { ds_read frag subtile | stage 1 half-tile (2 gload_lds) | sched_barrier
//     s_barrier | setprio(1) 16 MFMA setprio(0) | [vmcnt at ph4]
//     sched_barrier | s_barrier | sched_barrier }
// Stage schedule: ph1:Ak1(t+1)->buf b^1, ph2:Bk1(t+1)->b^1,
//                 ph3:Ak0(t+2)->b,      ph4:Bk0(t+2)->b.
// vmcnt(4) at each tile boundary retires everything except the 2 newest
// halves (tile t+2's k0), so all of tile t+1 is landed before first read.
// vmcnt(0) only entering the last tile.
//
// MODE 0: f32 out. MODE 1: bf16 out. MODE 3: gelu_tanh->bf16 (gate pass).
// MODE 4: out = gate[idx]*acc -> bf16 (up pass, in-place over gate is safe).
// MODE 5: fused QKV: tn 0-7 -> Wq/Q[4096][2048]; 8-11 -> Wk/K[4096][1024];
//         12-15 -> Wv/V^T[b][n][s].
// ---------------------------------------------------------------------------
__device__ __forceinline__ void stage_half(const bf16* __restrict__ src,
                                           bf16* lds_half, int K, int kcol0,
                                           int w, int l) {
    const int r = w * 16 + (l >> 2);                    // row within 128-row j-block
    const int s = (l & 3) ^ ((l >> 3) & 3);             // logical slot for this lane's
    const int c = kcol0 + s * 8;                        //   linear physical slot (l&3)
#pragma unroll
    for (int j = 0; j < 2; ++j)
        ASYNC16(lds_half + (j * 512 + w * 64) * 8,
                src + (size_t)(j * 128 + r) * K + c);
}

template <int MODE>
__global__ __launch_bounds__(512, 2)
void gemm8p(const bf16* __restrict__ A, const bf16* __restrict__ B0,
            const bf16* __restrict__ B1, const bf16* __restrict__ B2,
            void* __restrict__ C0, bf16* __restrict__ C1, bf16* __restrict__ C2,
            const bf16* __restrict__ gate, int M, int N, int K) {
    __shared__ __align__(16) bf16 lds[2 * 32768];   // 128 KiB
    const int tid = threadIdx.x;
    const int l = tid & 63, w = tid >> 6;
    const int lq = l & 15, quad = l >> 4;
    const int wm = w >> 2, wn = w & 3;              // 2M x 4N wave grid
    const int pq = (quad ^ ((lq >> 1) & 3)) * 8;    // swizzled read slot (elems)

    // bijective XCD-aware swizzle (grid always %8==0 here), tm-major decode
    const int ntm = M >> 8;
    const int nwg = gridDim.x, bid = blockIdx.x;
    const int q8 = nwg >> 3, r8 = nwg & 7;
    const int xcd = bid & 7, loc = bid >> 3;
    const int wg = (xcd < r8 ? xcd * (q8 + 1) : r8 * (q8 + 1) + (xcd - r8) * q8) + loc;
    const int tm = wg % ntm, tn = wg / ntm;

    const bf16* Ab = A + (size_t)(tm << 8) * K;
    const bf16* Bb;
    int vreg = 0, col0 = tn << 8;
    if constexpr (MODE == 5) {
        if (tn < 8)       { Bb = B0 + (size_t)(tn << 8) * K;        vreg = 0; col0 = tn << 8; }
        else if (tn < 12) { Bb = B1 + (size_t)((tn - 8) << 8) * K;  vreg = 1; col0 = (tn - 8) << 8; }
        else              { Bb = B2 + (size_t)((tn - 12) << 8) * K; vreg = 2; col0 = (tn - 12) << 8; }
    } else {
        Bb = B0 + (size_t)(tn << 8) * K;
    }

    auto ldsA = [&](int buf, int kk) { return lds + buf * 32768 + kk * 8192; };
    auto ldsB = [&](int buf, int kk) { return lds + buf * 32768 + 16384 + kk * 8192; };

    const int NT = K >> 6;
    // prologue: tile0 fully + tile1 K0-halves; retire all but the last 2 halves
    stage_half(Ab, ldsA(0, 0), K, 0,  w, l);
    stage_half(Bb, ldsB(0, 0), K, 0,  w, l);
    stage_half(Ab, ldsA(0, 1), K, 32, w, l);
    stage_half(Bb, ldsB(0, 1), K, 32, w, l);
    stage_half(Ab, ldsA(1, 0), K, 64, w, l);
    stage_half(Bb, ldsB(1, 0), K, 64, w, l);
    asm volatile("s_waitcnt vmcnt(4)" ::: "memory");
    __builtin_amdgcn_sched_barrier(0);
    __builtin_amdgcn_s_barrier();
    __builtin_amdgcn_sched_barrier(0);

    f32x4 acc[8][4];
#pragma unroll
    for (int i = 0; i < 8; ++i)
#pragma unroll
        for (int j = 0; j < 4; ++j) acc[i][j] = (f32x4){0.f, 0.f, 0.f, 0.f};

    for (int t = 0; t < NT; ++t) {
        const int b = t & 1;
        bf16x8 bfr[4];
#pragma unroll
        for (int kk = 0; kk < 2; ++kk) {
            const bf16* Ah = ldsA(b, kk);
            const bf16* Bh = ldsB(b, kk);
#pragma unroll
            for (int mh = 0; mh < 2; ++mh) {
                // ---- phase (kk, mh): ds-read subtile (swizzled slots)
                bf16x8 af[4];
#pragma unroll
                for (int i = 0; i < 4; ++i)
                    af[i] = *(const bf16x8*)&Ah[(wm * 128 + mh * 64 + i * 16 + lq) * 32 + pq];
                if (mh == 0) {
#pragma unroll
                    for (int i = 0; i < 4; ++i)
                        bfr[i] = *(const bf16x8*)&Bh[(wn * 64 + i * 16 + lq) * 32 + pq];
                }
                // ---- stage one half-tile (see schedule proof in header)
                if (kk == 0 && mh == 0 && t + 1 < NT)
                    stage_half(Ab, ldsA(b ^ 1, 1), K, ((t + 1) << 6) + 32, w, l);
                if (kk == 0 && mh == 1 && t + 1 < NT)
                    stage_half(Bb, ldsB(b ^ 1, 1), K, ((t + 1) << 6) + 32, w, l);
                if (kk == 1 && mh == 0 && t + 2 < NT)
                    stage_half(Ab, ldsA(b, 0), K, (t + 2) << 6, w, l);
                if (kk == 1 && mh == 1 && t + 2 < NT)
                    stage_half(Bb, ldsB(b, 0), K, (t + 2) << 6, w, l);
                __builtin_amdgcn_sched_barrier(0);
                __builtin_amdgcn_s_barrier();
                __builtin_amdgcn_s_setprio(1);
#pragma unroll
                for (int mi = 0; mi < 4; ++mi)
#pragma unroll
                    for (int ni = 0; ni < 4; ++ni)
                        acc[mh * 4 + mi][ni] = __builtin_amdgcn_mfma_f32_16x16x32_bf16(
                            af[mi], bfr[ni], acc[mh * 4 + mi][ni], 0, 0, 0);
                __builtin_amdgcn_s_setprio(0);
                if (kk == 1 && mh == 1) {
                    if (t + 2 < NT)      asm volatile("s_waitcnt vmcnt(4)" ::: "memory");
                    else if (t + 1 < NT) asm volatile("s_waitcnt vmcnt(0)" ::: "memory");
                }
                __builtin_amdgcn_sched_barrier(0);
                __builtin_amdgcn_s_barrier();
                __builtin_amdgcn_sched_barrier(0);
            }
        }
    }

    // epilogue (C/D layout: col = lane&15, row = quad*4 + reg)
    const int r0base = (tm << 8) + wm * 128 + quad * 4;
    const int c0base = col0 + wn * 64 + lq;
#pragma unroll
    for (int mi = 0; mi < 8; ++mi) {
#pragma unroll
        for (int ni = 0; ni < 4; ++ni) {
            const int cc = c0base + ni * 16;
#pragma unroll
            for (int i = 0; i < 4; ++i) {
                const int rr = r0base + mi * 16 + i;
                const float v = acc[mi][ni][i];
                if constexpr (MODE == 0) {
                    ((float*)C0)[(size_t)rr * N + cc] = v;
                } else if constexpr (MODE == 1) {
                    ((bf16*)C0)[(size_t)rr * N + cc] = (bf16)v;
                } else if constexpr (MODE == 3) {
                    const float inner = 0.7978845608028654f * (v + 0.044715f * v * v * v);
                    ((bf16*)C0)[(size_t)rr * N + cc] = (bf16)(0.5f * v * (1.f + fast_tanh(inner)));
                } else if constexpr (MODE == 4) {
                    const size_t idx = (size_t)rr * N + cc;
                    ((bf16*)C0)[idx] = (bf16)((float)gate[idx] * v);
                } else {  // MODE 5: fused QKV
                    if (vreg == 0)      ((bf16*)C0)[(size_t)rr * 2048 + cc] = (bf16)v;
                    else if (vreg == 1) C1[(size_t)rr * 1024 + cc] = (bf16)v;
                    else                C2[((size_t)(rr >> 11) * 1024 + cc) * 2048 + (rr & 2047)] = (bf16)v;
                }
            }
        }
    }
}

// ---------------------------------------------------------------------------
// Flash attention (unchanged from passing version).
// ---------------------------------------------------------------------------
__global__ __launch_bounds__(256)
void attn_k(const bf16* __restrict__ Q, const bf16* __restrict__ Kb,
            const bf16* __restrict__ Vt, bf16* __restrict__ O) {
    const int qt = blockIdx.x & 31;
    const int bh = blockIdx.x >> 5;
    const int h = bh & 7, b = bh >> 3;
    const int kvh = h >> 1;
    const int tid = threadIdx.x, lane = tid & 63, wave = tid >> 6;
    const int lq = lane & 15, quad = lane >> 4;

    __shared__ __align__(16) bf16 Ks[32 * 264];
    __shared__ __align__(16) bf16 VTs[256 * 40];
    __shared__ __align__(16) bf16 Ps[64 * 40];

    const bf16* qbase = Q + ((size_t)(b * NS + qt * 64)) * 2048 + h * 256;
    const bf16* kbase = Kb + (size_t)(b * NS) * 1024 + kvh * 256;
    const bf16* vbase = Vt + (size_t)b * 1024 * 2048 + (size_t)(kvh * 256) * 2048;

    bf16x8 aq[8];
#pragma unroll
    for (int ks = 0; ks < 8; ++ks)
        aq[ks] = *(const bf16x8*)&qbase[(size_t)(wave * 16 + lq) * 2048 + ks * 32 + quad * 8];

    f32x4 acco[16];
#pragma unroll
    for (int i = 0; i < 16; ++i) acco[i] = (f32x4){0.f, 0.f, 0.f, 0.f};
    float m_old[4] = {-1e30f, -1e30f, -1e30f, -1e30f};
    float l_old[4] = {0.f, 0.f, 0.f, 0.f};

    const int ktmax = 2 * qt + 1;
    for (int kt = 0; kt <= ktmax; ++kt) {
        __syncthreads();
#pragma unroll
        for (int j = 0; j < 4; ++j) {
            const int c = j * 256 + tid;
            const int r = c >> 5, c8 = (c & 31) * 8;
            *(uint4*)&Ks[r * 264 + c8] = *(const uint4*)&kbase[(size_t)(kt * 32 + r) * 1024 + c8];
        }
#pragma unroll
        for (int j = 0; j < 4; ++j) {
            const int c = j * 256 + tid;
            const int d = c >> 2, s8 = (c & 3) * 8;
            *(uint4*)&VTs[d * 40 + s8] = *(const uint4*)&vbase[(size_t)d * 2048 + kt * 32 + s8];
        }
        __syncthreads();

        f32x4 accs[2];
        accs[0] = (f32x4){0.f, 0.f, 0.f, 0.f};
        accs[1] = (f32x4){0.f, 0.f, 0.f, 0.f};
#pragma unroll
        for (int ks = 0; ks < 8; ++ks) {
#pragma unroll
            for (int nt = 0; nt < 2; ++nt) {
                const bf16x8 bk = *(const bf16x8*)&Ks[(nt * 16 + lq) * 264 + ks * 32 + quad * 8];
                accs[nt] = __builtin_amdgcn_mfma_f32_16x16x32_bf16(aq[ks], bk, accs[nt], 0, 0, 0);
            }
        }

        const bool diag = (kt >= 2 * qt);
        float p[2][4], rmax[4], rsum[4];
#pragma unroll
        for (int i = 0; i < 4; ++i) rmax[i] = -1e30f;
#pragma unroll
        for (int nt = 0; nt < 2; ++nt)
#pragma unroll
            for (int i = 0; i < 4; ++i) {
                float v = accs[nt][i] * SCALE_F;
                v = SOFTCAP_F * fast_tanh(v * (1.f / SOFTCAP_F));
                if (diag) {
                    const int qabs = qt * 64 + wave * 16 + quad * 4 + i;
                    const int kabs = kt * 32 + nt * 16 + lq;
                    if (kabs > qabs) v = -1e30f;
                }
                p[nt][i] = v;
                rmax[i] = fmaxf(rmax[i], v);
            }
#pragma unroll
        for (int i = 0; i < 4; ++i)
#pragma unroll
            for (int off = 8; off; off >>= 1) rmax[i] = fmaxf(rmax[i], __shfl_xor(rmax[i], off));

        float alpha[4];
#pragma unroll
        for (int i = 0; i < 4; ++i) {
            const float mn = fmaxf(m_old[i], rmax[i]);
            alpha[i] = __expf(m_old[i] - mn);
            m_old[i] = mn;
            rsum[i] = 0.f;
        }
#pragma unroll
        for (int nt = 0; nt < 2; ++nt)
#pragma unroll
            for (int i = 0; i < 4; ++i) {
                const float e = __expf(p[nt][i] - m_old[i]);
                p[nt][i] = e;
                rsum[i] += e;
            }
#pragma unroll
        for (int i = 0; i < 4; ++i) {
#pragma unroll
            for (int off = 8; off; off >>= 1) rsum[i] += __shfl_xor(rsum[i], off);
            l_old[i] = l_old[i] * alpha[i] + rsum[i];
        }
#pragma unroll
        for (int dt = 0; dt < 16; ++dt)
#pragma unroll
            for (int i = 0; i < 4; ++i) acco[dt][i] *= alpha[i];

#pragma unroll
        for (int nt = 0; nt < 2; ++nt)
#pragma unroll
            for (int i = 0; i < 4; ++i)
                Ps[(wave * 16 + quad * 4 + i) * 40 + nt * 16 + lq] = (bf16)p[nt][i];

        const bf16x8 ap = *(const bf16x8*)&Ps[(wave * 16 + lq) * 40 + quad * 8];
#pragma unroll
        for (int dt = 0; dt < 16; ++dt) {
            const bf16x8 bv = *(const bf16x8*)&VTs[(dt * 16 + lq) * 40 + quad * 8];
            acco[dt] = __builtin_amdgcn_mfma_f32_16x16x32_bf16(ap, bv, acco[dt], 0, 0, 0);
        }
    }

    bf16* obase = O + ((size_t)(b * NS + qt * 64 + wave * 16)) * 2048 + h * 256;
    float linv[4];
#pragma unroll
    for (int i = 0; i < 4; ++i) linv[i] = 1.f / l_old[i];
#pragma unroll
    for (int dt = 0; dt < 16; ++dt)
#pragma unroll
        for (int i = 0; i < 4; ++i)
            obase[(size_t)(quad * 4 + i) * 2048 + dt * 16 + lq] = (bf16)(acco[dt][i] * linv[i]);
}

// ---------------------------------------------------------------------------
// Host-side orchestration
// ---------------------------------------------------------------------------
extern "C" void kernel_launch(void* const* d_in, const int* in_sizes, int n_in,
                              void* d_out, int out_size, void* d_ws, size_t ws_size,
                              hipStream_t stream) {
    const float* x    = (const float*)d_in[0];
    // d_in[1] = mask (causal, reconstructed analytically)
    float* wq   = (float*)d_in[2];
    float* wk   = (float*)d_in[3];
    float* wv   = (float*)d_in[4];
    float* wo   = (float*)d_in[5];
    float* wg   = (float*)d_in[6];
    float* wu   = (float*)d_in[7];
    float* wd   = (float*)d_in[8];
    const float* g_in = (const float*)d_in[9];
    const float* g_pa = (const float*)d_in[10];
    const float* g_pf = (const float*)d_in[11];
    const float* g_po = (const float*)d_in[12];
    float* out = (float*)d_out;

    uint8_t* ws = (uint8_t*)d_ws;
    size_t off = 0;
    auto alloc = [&](size_t bytes) {
        void* p = ws + off;
        off += (bytes + 255) & ~(size_t)255;
        return p;
    };
    // total ws footprint: ~191 MB
    bf16* temp   = (bf16*)alloc((size_t)9216 * 1152 * 2);      // 21.2 MB transpose temp
    bf16* h_bf   = (bf16*)alloc((size_t)NROWS * 2304 * 2);     // 18.9 MB (reused as f_bf)
    uint8_t* R   = (uint8_t*)alloc((size_t)NROWS * 9216 * 2);  // 75.5 MB phased region
    float* tmp1  = (float*)alloc((size_t)NROWS * 2304 * 4);    // 37.7 MB attn_out / mlp_out
    float* h2    = (float*)alloc((size_t)NROWS * 2304 * 4);    // 37.7 MB
    (void)ws_size; (void)in_sizes; (void)n_in; (void)out_size;

    // phase-A views of R (dead before geglu writes mlp_in over them)
    bf16* q_bf   = (bf16*)R;                                     // 16.8 MB
    bf16* k_bf   = (bf16*)(R + (size_t)16777216);                //  8.4 MB
    bf16* v_t    = (bf16*)(R + (size_t)16777216 + 8388608);      //  8.4 MB
    bf16* o_bf   = (bf16*)(R + (size_t)16777216 + 2 * 8388608);  // 16.8 MB
    bf16* mlp_in = (bf16*)R;                                     // 75.5 MB (phase B; gate written in-place)

    // ---- in-place weight conversion: f32 [K][N] -> bf16 [N][K] at same base
    auto convert_weight = [&](float* W, int K, int N) {
        const int hK = K >> 1;
        const int blks = (hK >> 6) * (N >> 6);
        transpose_cvt_part<<<blks, 256, 0, stream>>>(W, N, 0, temp, hK, 0);
        transpose_cvt_part<<<blks, 256, 0, stream>>>(W, N, hK, (bf16*)W, K, hK);
        const int total = N * (hK >> 3);
        copy_expand<<<(total + 255) / 256, 256, 0, stream>>>(temp, (bf16*)W, hK, K, total);
    };
    convert_weight(wq, 2304, 2048);
    convert_weight(wk, 2304, 1024);
    convert_weight(wv, 2304, 1024);
    convert_weight(wo, 2048, 2304);
    convert_weight(wg, 2304, 9216);
    convert_weight(wu, 2304, 9216);
    convert_weight(wd, 9216, 2304);
    const bf16* wq_t = (const bf16*)wq;
    const bf16* wk_t = (const bf16*)wk;
    const bf16* wv_t = (const bf16*)wv;
    const bf16* wo_t = (const bf16*)wo;
    const bf16* wg_t = (const bf16*)wg;
    const bf16* wu_t = (const bf16*)wu;
    const bf16* wd_t = (const bf16*)wd;

    // h = rmsnorm(x, g_in) -> bf16
    rmsnorm_k<false, true><<<NROWS, 256, 0, stream>>>(x, nullptr, g_in, h_bf);

    // fused QKV projection: one pass over A, grid 16x16 = 256 blocks (full fill)
    gemm8p<5><<<16 * 16, 512, 0, stream>>>(h_bf, wq_t, wk_t, wv_t,
                                           q_bf, k_bf, v_t, nullptr,
                                           NROWS, 4096, 2304);

    // RoPE in place on q,k
    rope_k<<<(NROWS * 12 * 128) / 256, 256, 0, stream>>>(q_bf, k_bf);

    // attention
    attn_k<<<NB * NHEADS * (NS / 64), 256, 0, stream>>>(q_bf, k_bf, v_t, o_bf);

    // O projection -> f32
    gemm8p<0><<<16 * 9, 512, 0, stream>>>(o_bf, wo_t, nullptr, nullptr,
                                          tmp1, nullptr, nullptr, nullptr,
                                          NROWS, 2304, 2048);

    // h2 = x + rmsnorm(attn_out, g_post_attn)
    rmsnorm_k<true, false><<<NROWS, 256, 0, stream>>>(tmp1, x, g_pa, h2);
    // f = rmsnorm(h2, g_pre_ff) -> bf16 (reuse h_bf)
    rmsnorm_k<false, true><<<NROWS, 256, 0, stream>>>(h2, nullptr, g_pf, h_bf);

    // GeGLU as two pipelined passes over R (q/k/v/o dead):
    //   pass 1: gate = gelu(f @ wg) -> R;  pass 2: mlp_in = gate * (f @ wu) in-place
    gemm8p<3><<<16 * 36, 512, 0, stream>>>(h_bf, wg_t, nullptr, nullptr,
                                           mlp_in, nullptr, nullptr, nullptr,
                                           NROWS, 9216, 2304);
    gemm8p<4><<<16 * 36, 512, 0, stream>>>(h_bf, wu_t, nullptr, nullptr,
                                           mlp_in, nullptr, nullptr, mlp_in,
                                           NROWS, 9216, 2304);

    // down projection -> f32 (reuse tmp1)
    gemm8p<0><<<16 * 9, 512, 0, stream>>>(mlp_in, wd_t, nullptr, nullptr,
                                          tmp1, nullptr, nullptr, nullptr,
                                          NROWS, 2304, 9216);

    // out = h2 + rmsnorm(mlp_out, g_post_ff)
    rmsnorm_k<true, false><<<NROWS, 256, 0, stream>>>(tmp1, h2, g_po, (void*)out);
}

// Round 4
// 1488.815 us; speedup vs baseline: 1.0585x; 1.0585x over previous
//
#include <hip/hip_runtime.h>
#include <hip/hip_bf16.h>
#include <cstdint>
#include <cstddef>

typedef __bf16 bf16;
typedef __bf16 bf16x8 __attribute__((ext_vector_type(8)));
typedef __bf16 bf16x4v __attribute__((ext_vector_type(4)));
typedef float f32x4 __attribute__((ext_vector_type(4)));

#define NB 2
#define NS 2048
#define NHID 2304
#define NHEADS 8
#define NKVH 4
#define HDIM 256
#define NFF 9216
#define NROWS (NB * NS)      // 4096
#define SCALE_F 0.0625f      // 256^-0.5
#define SOFTCAP_F 50.0f

// async global->LDS DMA, 16B per lane; LDS dest = wave-uniform base + lane*16
#define ASYNC16(ldsp, gp)                                                     \
    __builtin_amdgcn_global_load_lds(                                         \
        (__attribute__((address_space(1))) void*)(gp),                        \
        (__attribute__((address_space(3))) void*)(ldsp), 16, 0, 0)

__device__ __forceinline__ float fast_tanh(float x) {
    x = fminf(fmaxf(x, -10.f), 10.f);
    float e = __expf(2.f * x);
    return (e - 1.f) / (e + 1.f);
}

// ---------------------------------------------------------------------------
// Partial transpose+convert: reads W[k][n] f32 for k in [k0, k0+64*gridK),
// writes bf16 dst[n*dstK + dstOff + (k-k0)].  64x64 tiles.
// ---------------------------------------------------------------------------
__global__ __launch_bounds__(256)
void transpose_cvt_part(const float* __restrict__ W, int N, int k0,
                        bf16* __restrict__ dst, int dstK, int dstOff) {
    __shared__ float tile[64][65];
    const int ntiles = N >> 6;
    const int tk = blockIdx.x / ntiles, tn = blockIdx.x % ntiles;
    const int kk0 = k0 + (tk << 6), n0 = tn << 6;
    const int tr = threadIdx.x >> 4, tc = threadIdx.x & 15;
#pragma unroll
    for (int j = 0; j < 4; ++j) {
        const int r = j * 16 + tr;
        const float4 v = *(const float4*)&W[(size_t)(kk0 + r) * N + n0 + tc * 4];
        tile[r][tc * 4 + 0] = v.x; tile[r][tc * 4 + 1] = v.y;
        tile[r][tc * 4 + 2] = v.z; tile[r][tc * 4 + 3] = v.w;
    }
    __syncthreads();
#pragma unroll
    for (int j = 0; j < 4; ++j) {
        const int n = j * 16 + tr;
        bf16x4v o;
        o.x = (bf16)tile[tc * 4 + 0][n];
        o.y = (bf16)tile[tc * 4 + 1][n];
        o.z = (bf16)tile[tc * 4 + 2][n];
        o.w = (bf16)tile[tc * 4 + 3][n];
        *(bf16x4v*)&dst[(size_t)(n0 + n) * dstK + dstOff + (tk << 6) + tc * 4] = o;
    }
}

// copy temp[n][0..srcK) -> dst[n*dstK + 0..srcK), 16B chunks
__global__ __launch_bounds__(256)
void copy_expand(const bf16* __restrict__ src, bf16* __restrict__ dst,
                 int srcK, int dstK, int total) {
    const int idx = blockIdx.x * 256 + threadIdx.x;
    if (idx >= total) return;
    const int cpr = srcK >> 3;
    const int n = idx / cpr, c = idx % cpr;
    *(uint4*)&dst[(size_t)n * dstK + c * 8] = *(const uint4*)&src[(size_t)n * srcK + c * 8];
}

// ---------------------------------------------------------------------------
// RMSNorm: out = [res +] rmsnorm(src, g).  One block per row, 256 thr, H=2304.
// ---------------------------------------------------------------------------
template <bool ADD, bool OBF>
__global__ __launch_bounds__(256)
void rmsnorm_k(const float* __restrict__ src, const float* __restrict__ res,
               const float* __restrict__ g, void* __restrict__ out) {
    const int row = blockIdx.x;
    const float* xr = src + (size_t)row * NHID;
    float vals[9];
    float ss = 0.f;
#pragma unroll
    for (int j = 0; j < 9; ++j) {
        vals[j] = xr[threadIdx.x + j * 256];
        ss += vals[j] * vals[j];
    }
#pragma unroll
    for (int off = 32; off > 0; off >>= 1) ss += __shfl_xor(ss, off);
    __shared__ float wss[4];
    if ((threadIdx.x & 63) == 0) wss[threadIdx.x >> 6] = ss;
    __syncthreads();
    const float scale = rsqrtf((wss[0] + wss[1] + wss[2] + wss[3]) * (1.f / NHID) + 1e-6f);
#pragma unroll
    for (int j = 0; j < 9; ++j) {
        const int c = threadIdx.x + j * 256;
        float v = vals[j] * scale * (1.f + g[c]);
        if constexpr (ADD) v += res[(size_t)row * NHID + c];
        if constexpr (OBF) ((bf16*)out)[(size_t)row * NHID + c] = (bf16)v;
        else               ((float*)out)[(size_t)row * NHID + c] = v;
    }
}

// ---------------------------------------------------------------------------
// RoPE in-place on bf16 q [4096][2048] and k [4096][1024].
// ---------------------------------------------------------------------------
__global__ __launch_bounds__(256)
void rope_k(bf16* __restrict__ q, bf16* __restrict__ k) {
    const int idx = blockIdx.x * 256 + threadIdx.x;
    const int i = idx & 127;
    const int t = idx >> 7;
    const int head = t % 12;
    const int row = t / 12;
    const int s = row & (NS - 1);
    const float ang = (float)s * exp2f(-(float)i * 0.10381025296523007f);
    float sn, cs;
    sincosf(ang, &sn, &cs);
    bf16* base = (head < 8) ? (q + (size_t)row * 2048 + head * 256 + i)
                            : (k + (size_t)row * 1024 + (head - 8) * 256 + i);
    const float x1 = (float)base[0], x2 = (float)base[128];
    base[0]   = (bf16)(x1 * cs - x2 * sn);
    base[128] = (bf16)(x2 * cs + x1 * sn);
}

// ---------------------------------------------------------------------------
// gemm8p: 8-phase pipelined 256x256-tile GEMM.  C[M][N] = A[M][K] @ Bt[N][K]^T.
// 512 thr = 8 waves (2M x 4N), per-wave 128x64 output = acc[8][4].
// BK=64 split into K-halves of 32.  LDS 128 KiB = 2 buf x {A,B} x 2 halves.
//
// T2 swizzle (rule #21, both-sides): logical 16B slot s of a 64-B row lives
// at physical slot s ^ ((row>>1)&3); applied to the global source k-offset
// in stage_half and to the ds_read slot (pq).  Verified conflict-free
// (SQ_LDS_BANK_CONFLICT = 0 in r3).
//
// r4 schedule changes (theory: exposed-latency, not LDS-BW, is the stall):
//  * stage-early: gload_lds issued at phase TOP (max in-flight coverage).
//  * shallow waits: TWO vmcnt(8) per K-tile instead of one vmcnt(4):
//      issue: ph1 A1(t+1)->b^1k1, ph2 B1(t+1), ph3 A0(t+2)->b k0, ph4 B0(t+2)
//      queue trace (steady, 2 loads/stage): entering t: <=8 outstanding
//      [A1B1(t), A0B0(t+1)].  ph1 +2, ph2 +2 -> <=12; W2=vmcnt(8) retires
//      oldest 4 = A1B1(t) (needed ph3).  ph3 +2, ph4 +2 -> <=12;
//      W1=vmcnt(8) retires A0B0(t+1) (needed t+1 ph1).  Each wait retires 4
//      loads issued ~6 phases (~2500 cy) earlier -> covers HBM-cold misses.
//      vmcnt(0) only entering the last tile.  Prologue: 12 loads, vmcnt(4).
//  * sched_barrier(0) ONLY before each stage group (pins the prior phase's
//      MFMAs + their lgkm waits above the DMA that overwrites the region
//      those reads used; all other motion freed -> compiler emits counted
//      lgkmcnt inside the MFMA cluster, m141 anti-pinning lesson).
//      Read-vs-DMA race safety: a wave's reads of a region are lgkm-drained
//      by its own MFMAs before it passes the phase-end barrier, and the
//      overwriting stage is issued after that barrier by every wave.
//  * bfr read before af (first MFMA waits on oldest reads).
//
// MODE 0: f32 out. MODE 1: bf16 out. MODE 3: gelu_tanh->bf16 (gate pass).
// MODE 4: out = gate[idx]*acc -> bf16 (up pass, in-place over gate is safe).
// MODE 5: fused QKV: tn 0-7 -> Wq/Q[4096][2048]; 8-11 -> Wk/K[4096][1024];
//         12-15 -> Wv/V^T[b][n][s].
// ---------------------------------------------------------------------------
__device__ __forceinline__ void stage_half(const bf16* __restrict__ src,
                                           bf16* lds_half, int K, int kcol0,
                                           int w, int l) {
    const int r = w * 16 + (l >> 2);                    // row within 128-row j-block
    const int s = (l & 3) ^ ((l >> 3) & 3);             // pre-swizzled source slot
    const int c = kcol0 + s * 8;
#pragma unroll
    for (int j = 0; j < 2; ++j)
        ASYNC16(lds_half + (j * 512 + w * 64) * 8,
                src + (size_t)(j * 128 + r) * K + c);
}

template <int MODE>
__global__ __launch_bounds__(512, 2)
void gemm8p(const bf16* __restrict__ A, const bf16* __restrict__ B0,
            const bf16* __restrict__ B1, const bf16* __restrict__ B2,
            void* __restrict__ C0, bf16* __restrict__ C1, bf16* __restrict__ C2,
            const bf16* __restrict__ gate, int M, int N, int K) {
    __shared__ __align__(16) bf16 lds[2 * 32768];   // 128 KiB
    const int tid = threadIdx.x;
    const int l = tid & 63, w = tid >> 6;
    const int lq = l & 15, quad = l >> 4;
    const int wm = w >> 2, wn = w & 3;              // 2M x 4N wave grid
    const int pq = (quad ^ ((lq >> 1) & 3)) * 8;    // swizzled read slot (elems)

    // bijective XCD-aware swizzle (grid always %8==0 here), tm-major decode
    const int ntm = M >> 8;
    const int nwg = gridDim.x, bid = blockIdx.x;
    const int q8 = nwg >> 3, r8 = nwg & 7;
    const int xcd = bid & 7, loc = bid >> 3;
    const int wg = (xcd < r8 ? xcd * (q8 + 1) : r8 * (q8 + 1) + (xcd - r8) * q8) + loc;
    const int tm = wg % ntm, tn = wg / ntm;

    const bf16* Ab = A + (size_t)(tm << 8) * K;
    const bf16* Bb;
    int vreg = 0, col0 = tn << 8;
    if constexpr (MODE == 5) {
        if (tn < 8)       { Bb = B0 + (size_t)(tn << 8) * K;        vreg = 0; col0 = tn << 8; }
        else if (tn < 12) { Bb = B1 + (size_t)((tn - 8) << 8) * K;  vreg = 1; col0 = (tn - 8) << 8; }
        else              { Bb = B2 + (size_t)((tn - 12) << 8) * K; vreg = 2; col0 = (tn - 12) << 8; }
    } else {
        Bb = B0 + (size_t)(tn << 8) * K;
    }

    auto ldsA = [&](int buf, int kk) { return lds + buf * 32768 + kk * 8192; };
    auto ldsB = [&](int buf, int kk) { return lds + buf * 32768 + 16384 + kk * 8192; };

    const int NT = K >> 6;
    // prologue: tile0 fully + tile1 K0-halves; retire all but the last 2 halves
    stage_half(Ab, ldsA(0, 0), K, 0,  w, l);
    stage_half(Bb, ldsB(0, 0), K, 0,  w, l);
    stage_half(Ab, ldsA(0, 1), K, 32, w, l);
    stage_half(Bb, ldsB(0, 1), K, 32, w, l);
    stage_half(Ab, ldsA(1, 0), K, 64, w, l);
    stage_half(Bb, ldsB(1, 0), K, 64, w, l);
    asm volatile("s_waitcnt vmcnt(4)" ::: "memory");
    __builtin_amdgcn_s_barrier();

    f32x4 acc[8][4];
#pragma unroll
    for (int i = 0; i < 8; ++i)
#pragma unroll
        for (int j = 0; j < 4; ++j) acc[i][j] = (f32x4){0.f, 0.f, 0.f, 0.f};

    for (int t = 0; t < NT; ++t) {
        const int b = t & 1;
        bf16x8 bfr[4];
#pragma unroll
        for (int kk = 0; kk < 2; ++kk) {
            const bf16* Ah = ldsA(b, kk);
            const bf16* Bh = ldsB(b, kk);
#pragma unroll
            for (int mh = 0; mh < 2; ++mh) {
                // ---- stage-early: issue this phase's half-tile DMA first
                __builtin_amdgcn_sched_barrier(0);
                if (kk == 0 && mh == 0 && t + 1 < NT)
                    stage_half(Ab, ldsA(b ^ 1, 1), K, ((t + 1) << 6) + 32, w, l);
                if (kk == 0 && mh == 1 && t + 1 < NT)
                    stage_half(Bb, ldsB(b ^ 1, 1), K, ((t + 1) << 6) + 32, w, l);
                if (kk == 1 && mh == 0 && t + 2 < NT)
                    stage_half(Ab, ldsA(b, 0), K, (t + 2) << 6, w, l);
                if (kk == 1 && mh == 1 && t + 2 < NT)
                    stage_half(Bb, ldsB(b, 0), K, (t + 2) << 6, w, l);
                // ---- ds_read frag subtile (bfr first: oldest reads feed
                //      the first MFMA via counted lgkmcnt)
                if (mh == 0) {
#pragma unroll
                    for (int i = 0; i < 4; ++i)
                        bfr[i] = *(const bf16x8*)&Bh[(wn * 64 + i * 16 + lq) * 32 + pq];
                }
                bf16x8 af[4];
#pragma unroll
                for (int i = 0; i < 4; ++i)
                    af[i] = *(const bf16x8*)&Ah[(wm * 128 + mh * 64 + i * 16 + lq) * 32 + pq];
                __builtin_amdgcn_s_barrier();
                __builtin_amdgcn_s_setprio(1);
#pragma unroll
                for (int mi = 0; mi < 4; ++mi)
#pragma unroll
                    for (int ni = 0; ni < 4; ++ni)
                        acc[mh * 4 + mi][ni] = __builtin_amdgcn_mfma_f32_16x16x32_bf16(
                            af[mi], bfr[ni], acc[mh * 4 + mi][ni], 0, 0, 0);
                __builtin_amdgcn_s_setprio(0);
                // ---- shallow vmcnt waits (see schedule proof in header)
                if (kk == 0 && mh == 1 && t + 1 < NT)
                    asm volatile("s_waitcnt vmcnt(8)" ::: "memory");   // W2: A1B1(t)
                if (kk == 1 && mh == 1) {
                    if (t + 2 < NT)      asm volatile("s_waitcnt vmcnt(8)" ::: "memory");  // W1
                    else if (t + 1 < NT) asm volatile("s_waitcnt vmcnt(0)" ::: "memory");
                }
                __builtin_amdgcn_s_barrier();
            }
        }
    }

    // epilogue (C/D layout: col = lane&15, row = quad*4 + reg)
    const int r0base = (tm << 8) + wm * 128 + quad * 4;
    const int c0base = col0 + wn * 64 + lq;
#pragma unroll
    for (int mi = 0; mi < 8; ++mi) {
#pragma unroll
        for (int ni = 0; ni < 4; ++ni) {
            const int cc = c0base + ni * 16;
#pragma unroll
            for (int i = 0; i < 4; ++i) {
                const int rr = r0base + mi * 16 + i;
                const float v = acc[mi][ni][i];
                if constexpr (MODE == 0) {
                    ((float*)C0)[(size_t)rr * N + cc] = v;
                } else if constexpr (MODE == 1) {
                    ((bf16*)C0)[(size_t)rr * N + cc] = (bf16)v;
                } else if constexpr (MODE == 3) {
                    const float inner = 0.7978845608028654f * (v + 0.044715f * v * v * v);
                    ((bf16*)C0)[(size_t)rr * N + cc] = (bf16)(0.5f * v * (1.f + fast_tanh(inner)));
                } else if constexpr (MODE == 4) {
                    const size_t idx = (size_t)rr * N + cc;
                    ((bf16*)C0)[idx] = (bf16)((float)gate[idx] * v);
                } else {  // MODE 5: fused QKV
                    if (vreg == 0)      ((bf16*)C0)[(size_t)rr * 2048 + cc] = (bf16)v;
                    else if (vreg == 1) C1[(size_t)rr * 1024 + cc] = (bf16)v;
                    else                C2[((size_t)(rr >> 11) * 1024 + cc) * 2048 + (rr & 2047)] = (bf16)v;
                }
            }
        }
    }
}

// ---------------------------------------------------------------------------
// Flash attention (unchanged from passing version).
// ---------------------------------------------------------------------------
__global__ __launch_bounds__(256)
void attn_k(const bf16* __restrict__ Q, const bf16* __restrict__ Kb,
            const bf16* __restrict__ Vt, bf16* __restrict__ O) {
    const int qt = blockIdx.x & 31;
    const int bh = blockIdx.x >> 5;
    const int h = bh & 7, b = bh >> 3;
    const int kvh = h >> 1;
    const int tid = threadIdx.x, lane = tid & 63, wave = tid >> 6;
    const int lq = lane & 15, quad = lane >> 4;

    __shared__ __align__(16) bf16 Ks[32 * 264];
    __shared__ __align__(16) bf16 VTs[256 * 40];
    __shared__ __align__(16) bf16 Ps[64 * 40];

    const bf16* qbase = Q + ((size_t)(b * NS + qt * 64)) * 2048 + h * 256;
    const bf16* kbase = Kb + (size_t)(b * NS) * 1024 + kvh * 256;
    const bf16* vbase = Vt + (size_t)b * 1024 * 2048 + (size_t)(kvh * 256) * 2048;

    bf16x8 aq[8];
#pragma unroll
    for (int ks = 0; ks < 8; ++ks)
        aq[ks] = *(const bf16x8*)&qbase[(size_t)(wave * 16 + lq) * 2048 + ks * 32 + quad * 8];

    f32x4 acco[16];
#pragma unroll
    for (int i = 0; i < 16; ++i) acco[i] = (f32x4){0.f, 0.f, 0.f, 0.f};
    float m_old[4] = {-1e30f, -1e30f, -1e30f, -1e30f};
    float l_old[4] = {0.f, 0.f, 0.f, 0.f};

    const int ktmax = 2 * qt + 1;
    for (int kt = 0; kt <= ktmax; ++kt) {
        __syncthreads();
#pragma unroll
        for (int j = 0; j < 4; ++j) {
            const int c = j * 256 + tid;
            const int r = c >> 5, c8 = (c & 31) * 8;
            *(uint4*)&Ks[r * 264 + c8] = *(const uint4*)&kbase[(size_t)(kt * 32 + r) * 1024 + c8];
        }
#pragma unroll
        for (int j = 0; j < 4; ++j) {
            const int c = j * 256 + tid;
            const int d = c >> 2, s8 = (c & 3) * 8;
            *(uint4*)&VTs[d * 40 + s8] = *(const uint4*)&vbase[(size_t)d * 2048 + kt * 32 + s8];
        }
        __syncthreads();

        f32x4 accs[2];
        accs[0] = (f32x4){0.f, 0.f, 0.f, 0.f};
        accs[1] = (f32x4){0.f, 0.f, 0.f, 0.f};
#pragma unroll
        for (int ks = 0; ks < 8; ++ks) {
#pragma unroll
            for (int nt = 0; nt < 2; ++nt) {
                const bf16x8 bk = *(const bf16x8*)&Ks[(nt * 16 + lq) * 264 + ks * 32 + quad * 8];
                accs[nt] = __builtin_amdgcn_mfma_f32_16x16x32_bf16(aq[ks], bk, accs[nt], 0, 0, 0);
            }
        }

        const bool diag = (kt >= 2 * qt);
        float p[2][4], rmax[4], rsum[4];
#pragma unroll
        for (int i = 0; i < 4; ++i) rmax[i] = -1e30f;
#pragma unroll
        for (int nt = 0; nt < 2; ++nt)
#pragma unroll
            for (int i = 0; i < 4; ++i) {
                float v = accs[nt][i] * SCALE_F;
                v = SOFTCAP_F * fast_tanh(v * (1.f / SOFTCAP_F));
                if (diag) {
                    const int qabs = qt * 64 + wave * 16 + quad * 4 + i;
                    const int kabs = kt * 32 + nt * 16 + lq;
                    if (kabs > qabs) v = -1e30f;
                }
                p[nt][i] = v;
                rmax[i] = fmaxf(rmax[i], v);
            }
#pragma unroll
        for (int i = 0; i < 4; ++i)
#pragma unroll
            for (int off = 8; off; off >>= 1) rmax[i] = fmaxf(rmax[i], __shfl_xor(rmax[i], off));

        float alpha[4];
#pragma unroll
        for (int i = 0; i < 4; ++i) {
            const float mn = fmaxf(m_old[i], rmax[i]);
            alpha[i] = __expf(m_old[i] - mn);
            m_old[i] = mn;
            rsum[i] = 0.f;
        }
#pragma unroll
        for (int nt = 0; nt < 2; ++nt)
#pragma unroll
            for (int i = 0; i < 4; ++i) {
                const float e = __expf(p[nt][i] - m_old[i]);
                p[nt][i] = e;
                rsum[i] += e;
            }
#pragma unroll
        for (int i = 0; i < 4; ++i) {
#pragma unroll
            for (int off = 8; off; off >>= 1) rsum[i] += __shfl_xor(rsum[i], off);
            l_old[i] = l_old[i] * alpha[i] + rsum[i];
        }
#pragma unroll
        for (int dt = 0; dt < 16; ++dt)
#pragma unroll
            for (int i = 0; i < 4; ++i) acco[dt][i] *= alpha[i];

#pragma unroll
        for (int nt = 0; nt < 2; ++nt)
#pragma unroll
            for (int i = 0; i < 4; ++i)
                Ps[(wave * 16 + quad * 4 + i) * 40 + nt * 16 + lq] = (bf16)p[nt][i];

        const bf16x8 ap = *(const bf16x8*)&Ps[(wave * 16 + lq) * 40 + quad * 8];
#pragma unroll
        for (int dt = 0; dt < 16; ++dt) {
            const bf16x8 bv = *(const bf16x8*)&VTs[(dt * 16 + lq) * 40 + quad * 8];
            acco[dt] = __builtin_amdgcn_mfma_f32_16x16x32_bf16(ap, bv, acco[dt], 0, 0, 0);
        }
    }

    bf16* obase = O + ((size_t)(b * NS + qt * 64 + wave * 16)) * 2048 + h * 256;
    float linv[4];
#pragma unroll
    for (int i = 0; i < 4; ++i) linv[i] = 1.f / l_old[i];
#pragma unroll
    for (int dt = 0; dt < 16; ++dt)
#pragma unroll
        for (int i = 0; i < 4; ++i)
            obase[(size_t)(quad * 4 + i) * 2048 + dt * 16 + lq] = (bf16)(acco[dt][i] * linv[i]);
}

// ---------------------------------------------------------------------------
// Host-side orchestration
// ---------------------------------------------------------------------------
extern "C" void kernel_launch(void* const* d_in, const int* in_sizes, int n_in,
                              void* d_out, int out_size, void* d_ws, size_t ws_size,
                              hipStream_t stream) {
    const float* x    = (const float*)d_in[0];
    // d_in[1] = mask (causal, reconstructed analytically)
    float* wq   = (float*)d_in[2];
    float* wk   = (float*)d_in[3];
    float* wv   = (float*)d_in[4];
    float* wo   = (float*)d_in[5];
    float* wg   = (float*)d_in[6];
    float* wu   = (float*)d_in[7];
    float* wd   = (float*)d_in[8];
    const float* g_in = (const float*)d_in[9];
    const float* g_pa = (const float*)d_in[10];
    const float* g_pf = (const float*)d_in[11];
    const float* g_po = (const float*)d_in[12];
    float* out = (float*)d_out;

    uint8_t* ws = (uint8_t*)d_ws;
    size_t off = 0;
    auto alloc = [&](size_t bytes) {
        void* p = ws + off;
        off += (bytes + 255) & ~(size_t)255;
        return p;
    };
    // total ws footprint: ~191 MB
    bf16* temp   = (bf16*)alloc((size_t)9216 * 1152 * 2);      // 21.2 MB transpose temp
    bf16* h_bf   = (bf16*)alloc((size_t)NROWS * 2304 * 2);     // 18.9 MB (reused as f_bf)
    uint8_t* R   = (uint8_t*)alloc((size_t)NROWS * 9216 * 2);  // 75.5 MB phased region
    float* tmp1  = (float*)alloc((size_t)NROWS * 2304 * 4);    // 37.7 MB attn_out / mlp_out
    float* h2    = (float*)alloc((size_t)NROWS * 2304 * 4);    // 37.7 MB
    (void)ws_size; (void)in_sizes; (void)n_in; (void)out_size;

    // phase-A views of R (dead before geglu writes mlp_in over them)
    bf16* q_bf   = (bf16*)R;                                     // 16.8 MB
    bf16* k_bf   = (bf16*)(R + (size_t)16777216);                //  8.4 MB
    bf16* v_t    = (bf16*)(R + (size_t)16777216 + 8388608);      //  8.4 MB
    bf16* o_bf   = (bf16*)(R + (size_t)16777216 + 2 * 8388608);  // 16.8 MB
    bf16* mlp_in = (bf16*)R;                                     // 75.5 MB (phase B; gate written in-place)

    // ---- in-place weight conversion: f32 [K][N] -> bf16 [N][K] at same base
    auto convert_weight = [&](float* W, int K, int N) {
        const int hK = K >> 1;
        const int blks = (hK >> 6) * (N >> 6);
        transpose_cvt_part<<<blks, 256, 0, stream>>>(W, N, 0, temp, hK, 0);
        transpose_cvt_part<<<blks, 256, 0, stream>>>(W, N, hK, (bf16*)W, K, hK);
        const int total = N * (hK >> 3);
        copy_expand<<<(total + 255) / 256, 256, 0, stream>>>(temp, (bf16*)W, hK, K, total);
    };
    convert_weight(wq, 2304, 2048);
    convert_weight(wk, 2304, 1024);
    convert_weight(wv, 2304, 1024);
    convert_weight(wo, 2048, 2304);
    convert_weight(wg, 2304, 9216);
    convert_weight(wu, 2304, 9216);
    convert_weight(wd, 9216, 2304);
    const bf16* wq_t = (const bf16*)wq;
    const bf16* wk_t = (const bf16*)wk;
    const bf16* wv_t = (const bf16*)wv;
    const bf16* wo_t = (const bf16*)wo;
    const bf16* wg_t = (const bf16*)wg;
    const bf16* wu_t = (const bf16*)wu;
    const bf16* wd_t = (const bf16*)wd;

    // h = rmsnorm(x, g_in) -> bf16
    rmsnorm_k<false, true><<<NROWS, 256, 0, stream>>>(x, nullptr, g_in, h_bf);

    // fused QKV projection: one pass over A, grid 16x16 = 256 blocks (full fill)
    gemm8p<5><<<16 * 16, 512, 0, stream>>>(h_bf, wq_t, wk_t, wv_t,
                                           q_bf, k_bf, v_t, nullptr,
                                           NROWS, 4096, 2304);

    // RoPE in place on q,k
    rope_k<<<(NROWS * 12 * 128) / 256, 256, 0, stream>>>(q_bf, k_bf);

    // attention
    attn_k<<<NB * NHEADS * (NS / 64), 256, 0, stream>>>(q_bf, k_bf, v_t, o_bf);

    // O projection -> f32
    gemm8p<0><<<16 * 9, 512, 0, stream>>>(o_bf, wo_t, nullptr, nullptr,
                                          tmp1, nullptr, nullptr, nullptr,
                                          NROWS, 2304, 2048);

    // h2 = x + rmsnorm(attn_out, g_post_attn)
    rmsnorm_k<true, false><<<NROWS, 256, 0, stream>>>(tmp1, x, g_pa, h2);
    // f = rmsnorm(h2, g_pre_ff) -> bf16 (reuse h_bf)
    rmsnorm_k<false, true><<<NROWS, 256, 0, stream>>>(h2, nullptr, g_pf, h_bf);

    // GeGLU as two pipelined passes over R (q/k/v/o dead):
    //   pass 1: gate = gelu(f @ wg) -> R;  pass 2: mlp_in = gate * (f @ wu) in-place
    gemm8p<3><<<16 * 36, 512, 0, stream>>>(h_bf, wg_t, nullptr, nullptr,
                                           mlp_in, nullptr, nullptr, nullptr,
                                           NROWS, 9216, 2304);
    gemm8p<4><<<16 * 36, 512, 0, stream>>>(h_bf, wu_t, nullptr, nullptr,
                                           mlp_in, nullptr, nullptr, mlp_in,
                                           NROWS, 9216, 2304);

    // down projection -> f32 (reuse tmp1)
    gemm8p<0><<<16 * 9, 512, 0, stream>>>(mlp_in, wd_t, nullptr, nullptr,
                                          tmp1, nullptr, nullptr, nullptr,
                                          NROWS, 2304, 9216);

    // out = h2 + rmsnorm(mlp_out, g_post_ff)
    rmsnorm_k<true, false><<<NROWS, 256, 0, stream>>>(tmp1, h2, g_po, (void*)out);
}